// Round 8
// baseline (687.196 us; speedup 1.0000x reference)
//
#include <hip/hip_runtime.h>
#include <hip/hip_bf16.h>

typedef __hip_bfloat16 bf16;
typedef __attribute__((ext_vector_type(8))) short short8;
typedef __attribute__((ext_vector_type(4))) float floatx4;

// ---- dtype helpers ----
__device__ inline float ldf(const float* p, size_t i) { return p[i]; }
__device__ inline float ldf(const bf16* p, size_t i) { return (float)p[i]; }
__device__ inline void stf(float* p, size_t i, float v) { p[i] = v; }
__device__ inline void stf(bf16* p, size_t i, float v) { p[i] = (bf16)v; }

// ---- 16B vector load of VEC elements -> fp32 lanes ----
__device__ inline void loadvec(const float* __restrict__ p, float* d) {   // VEC=4
    float4 v = *(const float4*)p;
    d[0] = v.x; d[1] = v.y; d[2] = v.z; d[3] = v.w;
}
__device__ inline void loadvec(const bf16* __restrict__ p, float* d) {    // VEC=8
    uint4 u = *(const uint4*)p;
    const unsigned* w = (const unsigned*)&u;
    #pragma unroll
    for (int j = 0; j < 4; ++j) {
        d[2 * j]     = __uint_as_float(w[j] << 16);
        d[2 * j + 1] = __uint_as_float(w[j] & 0xffff0000u);
    }
}
template <int VEC, typename TOut>
__device__ inline void storevec(TOut* __restrict__ p, const float* d) {
    if constexpr (sizeof(TOut) == 4) {
        #pragma unroll
        for (int j = 0; j < VEC; j += 4) {
            float4 v = {d[j], d[j + 1], d[j + 2], d[j + 3]};
            *(float4*)(p + j) = v;
        }
    } else {
        unsigned w[VEC / 2];
        #pragma unroll
        for (int j = 0; j < VEC / 2; ++j) {
            bf16 lo = (bf16)d[2 * j], hi = (bf16)d[2 * j + 1];
            w[j] = ((unsigned)*(unsigned short*)&hi << 16) | (unsigned)*(unsigned short*)&lo;
        }
        if constexpr (VEC == 8) *(uint4*)p = *(uint4*)&w[0];
        else                    *(uint2*)p = *(uint2*)&w[0];
    }
}

// ---------------------------------------------------------------- dtype detect
__global__ void detect_dtype_kernel(const unsigned short* __restrict__ x, int* __restrict__ flag) {
    __shared__ float s[256];
    float m = 0.0f;
    for (int i = threadIdx.x; i < 512; i += 256) {
        unsigned int u = ((unsigned int)x[i]) << 16;
        float v = __uint_as_float(u);
        if (!isnan(v)) m = fmaxf(m, fabsf(v));
    }
    s[threadIdx.x] = m;
    __syncthreads();
    for (int o = 128; o > 0; o >>= 1) {
        if (threadIdx.x < (unsigned)o) s[threadIdx.x] = fmaxf(s[threadIdx.x], s[threadIdx.x + o]);
        __syncthreads();
    }
    if (threadIdx.x == 0) flag[0] = (s[0] > 1e3f) ? 0 : 1;
}

// ---------------------------------------------------------------- fused converts
struct CvtJobs {
    const void* src[14];
    float* dst[14];
    int off[15];
    int cnt;
};
__global__ void cvt_fused_kernel(CvtJobs j, const int* __restrict__ flag) {
    int t = blockIdx.x * 256 + threadIdx.x;
    if (t >= j.off[j.cnt]) return;
    int k = 0;
    while (t >= j.off[k + 1]) ++k;
    int e = t - j.off[k];
    float v = *flag ? (float)((const bf16*)j.src[k])[e] : ((const float*)j.src[k])[e];
    j.dst[k][e] = v;
}

// W[K][N] (raw dtype per flag) -> Wt[N][K] bf16, three jobs fused
struct WtJobs {
    const void* src[3];
    bf16* dst[3];
    int K[3], N[3];
    int off[4];
};
__global__ void wt_fused_kernel(WtJobs j, const int* __restrict__ flag) {
    int t = blockIdx.x * 256 + threadIdx.x;
    if (t >= j.off[3]) return;
    int k_ = 0;
    while (t >= j.off[k_ + 1]) ++k_;
    int e = t - j.off[k_];
    int K = j.K[k_], Nn = j.N[k_];
    int n = e / K, kk = e % K;
    size_t si = (size_t)kk * Nn + n;
    float v = *flag ? (float)((const bf16*)j.src[k_])[si] : ((const float*)j.src[k_])[si];
    j.dst[k_][e] = (bf16)v;
}

__global__ void out_kernel(const float* __restrict__ in, void* __restrict__ out,
                           int n, const int* __restrict__ flag) {
    int i = blockIdx.x * blockDim.x + threadIdx.x;
    if (i >= n) return;
    if (*flag) ((bf16*)out)[i] = (bf16)in[i];
    else       ((float*)out)[i] = in[i];
}

// ---------------------------------------------------------------- CSR build
__global__ void zero_int_kernel(int* a, int n) {
    int i = blockIdx.x * blockDim.x + threadIdx.x;
    if (i < n) a[i] = 0;
}

__global__ void hist_kernel(const int* __restrict__ col, int* __restrict__ counts, int E) {
    int e = blockIdx.x * blockDim.x + threadIdx.x;
    if (e < E) atomicAdd(&counts[col[e]], 1);
}

// exclusive scan of counts -> offsets; also dis[i]=rsqrt(count+1) and counts[i]=0
__global__ void scan_dis_kernel(int* __restrict__ counts, int* __restrict__ offsets,
                                float* __restrict__ dis, int n) {
    __shared__ int sdata[1024];
    int carry = 0;
    if (threadIdx.x == 0) offsets[0] = 0;
    for (int base = 0; base < n; base += 1024) {
        int i = base + (int)threadIdx.x;
        int v = (i < n) ? counts[i] : 0;
        if (i < n) { dis[i] = rsqrtf((float)(v + 1)); counts[i] = 0; }
        sdata[threadIdx.x] = v;
        __syncthreads();
        for (int off = 1; off < 1024; off <<= 1) {
            int t = (threadIdx.x >= (unsigned)off) ? sdata[threadIdx.x - off] : 0;
            __syncthreads();
            sdata[threadIdx.x] += t;
            __syncthreads();
        }
        int inc = sdata[threadIdx.x] + carry;
        if (i < n) offsets[i + 1] = inc;
        carry += sdata[1023];
        __syncthreads();
    }
}

__global__ void fill_kernel(const int* __restrict__ row, const int* __restrict__ col,
                            const int* __restrict__ offsets, int* __restrict__ cursor,
                            int* __restrict__ csr_src, int E) {
    int e = blockIdx.x * blockDim.x + threadIdx.x;
    if (e < E) {
        int d = col[e];
        int pos = offsets[d] + atomicAdd(&cursor[d], 1);
        csr_src[pos] = row[e];
    }
}

// ---------------------------------------------------------------- aggregation
// legacy scalar version (tiny F: L0 F=3, L7 F=2) — reads dis[s] per edge
template <typename TIn, typename TOut>
__global__ void agg_kernel(const TIn* __restrict__ h, const int* __restrict__ offsets,
                           const int* __restrict__ csr_src, const float* __restrict__ dis,
                           const float* __restrict__ bias, TOut* __restrict__ out,
                           int n, int F, int add_bias, int relu) {
    long long idx = (long long)blockIdx.x * blockDim.x + threadIdx.x;
    long long total = (long long)n * F;
    if (idx >= total) return;
    int i = (int)(idx / F);
    int f = (int)(idx % F);
    float di = dis[i];
    float acc = di * ldf(h, (size_t)i * F + f);
    int e0 = offsets[i], e1 = offsets[i + 1];
    for (int e = e0; e < e1; ++e) {
        int s = csr_src[e];
        acc += dis[s] * ldf(h, (size_t)s * F + f);
    }
    acc *= di;
    if (add_bias) acc += bias[f];
    if (relu) acc = fmaxf(acc, 0.0f);
    stf(out, (size_t)idx, acc);
}

// vectorized, PRESCALED input (h holds g = dis⊙value, produced by upstream
// epilogue). out_i = di*(g_i + Σ_e g_s) (+b)(relu)(×di if SCALE_OUT -> g-form).
template <int F, int DO_BIAS, int DO_RELU, int SCALE_OUT, typename TIn, typename TOut>
__global__ __launch_bounds__(256) void agg_vec_kernel(
        const TIn* __restrict__ h, const int* __restrict__ offsets,
        const int* __restrict__ csr_src, const float* __restrict__ dis,
        const float* __restrict__ bias, TOut* __restrict__ out, int n) {
    constexpr int VEC = 16 / sizeof(TIn);
    constexpr int CPL = F / VEC;
    int t = blockIdx.x * 256 + threadIdx.x;
    if (t >= n * CPL) return;
    int i = t / CPL;
    int c = t % CPL;
    int fbase = c * VEC;
    float acc[VEC];
    loadvec(h + (size_t)i * F + fbase, acc);
    int e0 = offsets[i], e1 = offsets[i + 1];
    for (int e = e0; e < e1; ++e) {
        int s = csr_src[e];
        float tmp[VEC];
        loadvec(h + (size_t)s * F + fbase, tmp);
        #pragma unroll
        for (int v = 0; v < VEC; ++v) acc[v] += tmp[v];
    }
    float di = dis[i];
    #pragma unroll
    for (int v = 0; v < VEC; ++v) {
        acc[v] *= di;
        if (DO_BIAS) acc[v] += bias[fbase + v];
        if (DO_RELU) acc[v] = fmaxf(acc[v], 0.0f);
        if (SCALE_OUT) acc[v] *= di;
    }
    storevec<VEC>(out + (size_t)i * F + fbase, acc);
}

// ---------------------------------------------------------------- GEMMs
template <typename TIn, typename TOut>
__global__ void gemm_naive_kernel(const TIn* __restrict__ A, const float* __restrict__ W,
                                  const float* __restrict__ bias, TOut* __restrict__ C,
                                  int M, int Nc, int K, int add_bias, int relu) {
    long long idx = (long long)blockIdx.x * blockDim.x + threadIdx.x;
    long long total = (long long)M * Nc;
    if (idx >= total) return;
    int m = (int)(idx / Nc);
    int nc = (int)(idx % Nc);
    float acc = 0.0f;
    for (int k = 0; k < K; ++k)
        acc += ldf(A, (size_t)m * K + k) * W[(size_t)k * Nc + nc];
    if (add_bias) acc += bias[nc];
    if (relu) acc = fmaxf(acc, 0.0f);
    stf(C, (size_t)idx, acc);
}

// fp32 tiled GEMM (L1-L3): 64x64 tile, K%16==0, Nc%64==0.
// rowscale != nullptr: multiply final value by rowscale[gm] (applied LAST).
#define TM 64
#define TN 64
#define TK 16
template <typename TIn, typename TOut>
__global__ __launch_bounds__(256) void gemm_tiled_kernel(
        const TIn* __restrict__ A, const float* __restrict__ W,
        const float* __restrict__ bias, TOut* __restrict__ C,
        int M, int Nc, int K, int add_bias, int relu,
        const float* __restrict__ rowscale) {
    __shared__ float As[TK][TM + 1];
    __shared__ float Bs[TK][TN + 1];
    int bm = blockIdx.x * TM;
    int bn = blockIdx.y * TN;
    int tid = threadIdx.x;
    int tm = (tid >> 4) << 2;
    int tn = (tid & 15) << 2;
    float acc[4][4] = {};
    for (int k0 = 0; k0 < K; k0 += TK) {
        #pragma unroll
        for (int l = 0; l < 4; ++l) {
            int idx = tid + l * 256;
            int m = idx >> 4;
            int k = idx & 15;
            int gm = bm + m;
            As[k][m] = (gm < M) ? ldf(A, (size_t)gm * K + k0 + k) : 0.0f;
        }
        #pragma unroll
        for (int l = 0; l < 4; ++l) {
            int idx = tid + l * 256;
            int k = idx >> 6;
            int nn = idx & 63;
            Bs[k][nn] = W[(size_t)(k0 + k) * Nc + bn + nn];
        }
        __syncthreads();
        #pragma unroll
        for (int k = 0; k < TK; ++k) {
            float a[4], b[4];
            #pragma unroll
            for (int i = 0; i < 4; ++i) a[i] = As[k][tm + i];
            #pragma unroll
            for (int j = 0; j < 4; ++j) b[j] = Bs[k][tn + j];
            #pragma unroll
            for (int i = 0; i < 4; ++i)
                #pragma unroll
                for (int j = 0; j < 4; ++j) acc[i][j] += a[i] * b[j];
        }
        __syncthreads();
    }
    #pragma unroll
    for (int i = 0; i < 4; ++i) {
        int gm = bm + tm + i;
        if (gm >= M) continue;
        float rs = rowscale ? rowscale[gm] : 1.0f;
        #pragma unroll
        for (int j = 0; j < 4; ++j) {
            int gn = bn + tn + j;
            float v = acc[i][j];
            if (add_bias) v += bias[gn];
            if (relu) v = fmaxf(v, 0.0f);
            v *= rs;
            stf(C, (size_t)gm * Nc + gn, v);
        }
    }
}

// ---------------------------------------------------------------- MFMA GEMM
// C[M,Nc] = A[M,K](bf16) @ Bt[Nc,K](bf16)^T, fp32 accum. 128x128 tile, BK=32.
// Grid: (Nc/128, cdiv(M,128)) — N-blocks innermost so blocks sharing one A slab
// co-run (A fetched once into L2/L3).
// Staging: explicit uint4 global->reg->LDS (round-5 style). NOTE: async
// global_load_lds was tried (r6/r7) — zero speedup and implicated in 40 ms
// dispatch anomalies + post-timing corruption under graph replay. Keep VGPR
// staging.
// DO_SCALE: multiply by dis[gm] after bias/relu (emits g-form for the agg).
template <int DO_BIAS, int DO_RELU, int DO_SCALE, typename TOut>
__global__ __launch_bounds__(256) void gemm_mfma_kernel(
        const bf16* __restrict__ A,   // [M,K]
        const bf16* __restrict__ Bt,  // [Nc,K]
        const float* __restrict__ bias,
        const float* __restrict__ dis,
        TOut* __restrict__ C,         // [M,Nc]
        int M, int Nc, int K) {
    __shared__ bf16 As[128 * 32];
    __shared__ bf16 Bs[128 * 32];
    const int tid  = threadIdx.x;
    const int wave = tid >> 6;
    const int lane = tid & 63;
    const int bm = blockIdx.y * 128;
    const int bn = blockIdx.x * 128;
    const int wr = (wave >> 1) * 64;
    const int wc = (wave & 1) * 64;
    const int fm = lane & 15;
    const int fq = lane >> 4;
    const int fk = fq * 8;

    const int e0 = tid * 8;
    const int r0 = e0 >> 5, c0 = e0 & 31;
    const int e1 = (256 + tid) * 8;
    const int r1 = e1 >> 5, c1 = e1 & 31;
    int gmA0 = bm + r0; if (gmA0 > M - 1) gmA0 = M - 1;
    int gmA1 = bm + r1; if (gmA1 > M - 1) gmA1 = M - 1;

    floatx4 acc[4][4] = {};

    for (int k0 = 0; k0 < K; k0 += 32) {
        // issue staging loads into regs (overlaps prior iteration's MFMAs)
        uint4 va0 = *(const uint4*)(A  + (size_t)gmA0      * K + k0 + c0);
        uint4 va1 = *(const uint4*)(A  + (size_t)gmA1      * K + k0 + c1);
        uint4 vb0 = *(const uint4*)(Bt + (size_t)(bn + r0) * K + k0 + c0);
        uint4 vb1 = *(const uint4*)(Bt + (size_t)(bn + r1) * K + k0 + c1);
        __syncthreads();
        *(uint4*)(&As[e0]) = va0;
        *(uint4*)(&As[e1]) = va1;
        *(uint4*)(&Bs[e0]) = vb0;
        *(uint4*)(&Bs[e1]) = vb1;
        __syncthreads();
        short8 af[4], bfv[4];
        #pragma unroll
        for (int t = 0; t < 4; ++t) {
            af[t]  = *(const short8*)(&As[(wr + t * 16 + fm) * 32 + fk]);
            bfv[t] = *(const short8*)(&Bs[(wc + t * 16 + fm) * 32 + fk]);
        }
        #pragma unroll
        for (int mt = 0; mt < 4; ++mt)
            #pragma unroll
            for (int nt = 0; nt < 4; ++nt)
                acc[mt][nt] = __builtin_amdgcn_mfma_f32_16x16x32_bf16(
                    af[mt], bfv[nt], acc[mt][nt], 0, 0, 0);
    }

    #pragma unroll
    for (int mt = 0; mt < 4; ++mt) {
        #pragma unroll
        for (int r = 0; r < 4; ++r) {
            int gm = bm + wr + mt * 16 + fq * 4 + r;
            if (gm >= M) continue;
            float rs = DO_SCALE ? dis[gm] : 1.0f;
            #pragma unroll
            for (int nt = 0; nt < 4; ++nt) {
                int gn = bn + wc + nt * 16 + fm;
                float v = acc[mt][nt][r];
                if (DO_BIAS) v += bias[gn];
                if (DO_RELU) v = fmaxf(v, 0.0f);
                if (DO_SCALE) v *= rs;
                stf(C, (size_t)gm * Nc + gn, v);
            }
        }
    }
}

// ---------------------------------------------------------------- driver

static inline int cdiv(long long a, int b) { return (int)((a + b - 1) / b); }

extern "C" void kernel_launch(void* const* d_in, const int* in_sizes, int n_in,
                              void* d_out, int out_size, void* d_ws, size_t ws_size,
                              hipStream_t stream) {
    const int N = in_sizes[0] / 3;
    const int E = in_sizes[1] / 2;

    const int* edge_index = (const int*)d_in[1];
    const int* row = edge_index;       // sources
    const int* col = edge_index + E;   // destinations

    char* p = (char*)d_ws;
    auto alloc = [&](size_t bytes) {
        void* r = (void*)p;
        p += (bytes + 255) & ~(size_t)255;
        return r;
    };
    void* bufA    = alloc((size_t)N * 2048);   // max(N*1024 bf16, N*512 f32)
    void* bufB    = alloc((size_t)N * 1024);   // max(N*512 bf16, N*256 f32)
    float* dis    = (float*)alloc((size_t)N * sizeof(float));
    int* offsets  = (int*)alloc((size_t)(N + 1) * sizeof(int));
    int* cursor   = (int*)alloc((size_t)N * sizeof(int));
    int* csr_src  = (int*)alloc((size_t)E * sizeof(int));
    int* flag     = (int*)alloc(256);
    const int WfL[5] = {0, 1, 2, 3, 7};
    float* Wf[8] = {};
    float* bf_[8];
    for (int t = 0; t < 5; ++t) {
        int L = WfL[t];
        Wf[L] = (float*)alloc((size_t)in_sizes[2 + 2 * L] * sizeof(float));
    }
    for (int L = 0; L < 8; ++L)
        bf_[L] = (float*)alloc((size_t)in_sizes[3 + 2 * L] * sizeof(float));
    bf16* Wt4 = (bf16*)alloc((size_t)128 * 1024 * sizeof(bf16));
    bf16* Wt5 = (bf16*)alloc((size_t)1024 * 512 * sizeof(bf16));
    bf16* Wt6 = (bf16*)alloc((size_t)512 * 256 * sizeof(bf16));
    size_t needed = (size_t)(p - (char*)d_ws);
    if (ws_size < needed) return;

    float* fA = (float*)bufA;  bf16* hA = (bf16*)bufA;
    float* fB = (float*)bufB;  bf16* hB = (bf16*)bufB;

    const int T = 256;

    // ---- dtype detect ----
    detect_dtype_kernel<<<1, 256, 0, stream>>>((const unsigned short*)d_in[0], flag);

    // ---- fused fp32 converts: x, W{0,1,2,3,7}, b0..b7 (14 jobs) ----
    {
        CvtJobs cj{};
        int idx = 0, cum = 0;
        auto add = [&](const void* s, float* d, int n) {
            cj.src[idx] = s; cj.dst[idx] = d; cj.off[idx] = cum; cum += n; ++idx;
        };
        add(d_in[0], fA, N * 3);
        for (int t = 0; t < 5; ++t) {
            int L = WfL[t];
            add(d_in[2 + 2 * L], Wf[L], in_sizes[2 + 2 * L]);
        }
        for (int L = 0; L < 8; ++L)
            add(d_in[3 + 2 * L], bf_[L], in_sizes[3 + 2 * L]);
        cj.off[idx] = cum; cj.cnt = idx;
        cvt_fused_kernel<<<cdiv(cum, T), T, 0, stream>>>(cj, flag);
    }

    // ---- fused bf16 weight transposes ----
    {
        WtJobs wj{};
        wj.src[0] = d_in[2 + 2 * 4]; wj.dst[0] = Wt4; wj.K[0] = 128;  wj.N[0] = 1024;
        wj.src[1] = d_in[2 + 2 * 5]; wj.dst[1] = Wt5; wj.K[1] = 1024; wj.N[1] = 512;
        wj.src[2] = d_in[2 + 2 * 6]; wj.dst[2] = Wt6; wj.K[2] = 512;  wj.N[2] = 256;
        wj.off[0] = 0;
        wj.off[1] = 128 * 1024;
        wj.off[2] = 128 * 1024 + 1024 * 512;
        wj.off[3] = 128 * 1024 + 1024 * 512 + 512 * 256;
        wt_fused_kernel<<<cdiv(wj.off[3], T), T, 0, stream>>>(wj, flag);
    }

    // ---- CSR build ----
    zero_int_kernel<<<cdiv(N, T), T, 0, stream>>>(cursor, N);
    hist_kernel<<<cdiv(E, T), T, 0, stream>>>(col, cursor, E);
    scan_dis_kernel<<<1, 1024, 0, stream>>>(cursor, offsets, dis, N);
    fill_kernel<<<cdiv(E, T), T, 0, stream>>>(row, col, offsets, cursor, csr_src, E);

    // Layer schedule (dims 3,64,64,64,128,1024,512,256,2).
    // g-form convention: upstream epilogue stores dis[row]*value; PRESCALED
    // agg_vec then needs no per-edge dis gather.

    // L0: 3->64 aggFirst (legacy scalar agg), naive gemm (+b0,relu) -> fA
    agg_kernel<float, float><<<cdiv((long long)N * 3, T), T, 0, stream>>>(
        fA, offsets, csr_src, dis, nullptr, fB, N, 3, 0, 0);
    gemm_naive_kernel<float, float><<<cdiv((long long)N * 64, T), T, 0, stream>>>(
        fB, Wf[0], bf_[0], fA, N, 64, 3, 1, 1);

    // L1: gemm (rowscale=dis) -> fB (g-form); agg_vec (+b1,relu) -> fA
    {
        dim3 g(cdiv(N, TM), 64 / TN);
        gemm_tiled_kernel<float, float><<<g, 256, 0, stream>>>(
            fA, Wf[1], nullptr, fB, N, 64, 64, 0, 0, dis);
        agg_vec_kernel<64, 1, 1, 0, float, float><<<cdiv((long long)N * 16, T), T, 0, stream>>>(
            fB, offsets, csr_src, dis, bf_[1], fA, N);
    }

    // L2: gemm (rowscale) -> fB; agg_vec (+b2,relu,SCALE_OUT) -> fA (g-form for L3)
    {
        dim3 g(cdiv(N, TM), 64 / TN);
        gemm_tiled_kernel<float, float><<<g, 256, 0, stream>>>(
            fA, Wf[2], nullptr, fB, N, 64, 64, 0, 0, dis);
        agg_vec_kernel<64, 1, 1, 1, float, float><<<cdiv((long long)N * 16, T), T, 0, stream>>>(
            fB, offsets, csr_src, dis, bf_[2], fA, N);
    }

    // L3: aggFirst: agg_vec (g-form in) -> fB (plain); gemm (+b3,relu,rowscale) -> hA (g-form bf16)
    {
        agg_vec_kernel<64, 0, 0, 0, float, float><<<cdiv((long long)N * 16, T), T, 0, stream>>>(
            fA, offsets, csr_src, dis, nullptr, fB, N);
        dim3 g(cdiv(N, TM), 128 / TN);
        gemm_tiled_kernel<float, bf16><<<g, 256, 0, stream>>>(
            fB, Wf[3], bf_[3], hA, N, 128, 64, 1, 1, dis);
    }

    // L4: aggFirst: agg_vec (g-form in) -> hB (plain); MFMA (+b4,relu) -> hA
    {
        agg_vec_kernel<128, 0, 0, 0, bf16, bf16><<<cdiv((long long)N * 16, T), T, 0, stream>>>(
            hA, offsets, csr_src, dis, nullptr, hB, N);
        dim3 g(1024 / 128, cdiv(N, 128));
        gemm_mfma_kernel<1, 1, 0, bf16><<<g, 256, 0, stream>>>(hB, Wt4, bf_[4], dis, hA, N, 1024, 128);
    }

    // L5: MFMA (rowscale) -> hB (g-form); agg_vec (+b5,relu) -> hA
    {
        dim3 g(512 / 128, cdiv(N, 128));
        gemm_mfma_kernel<0, 0, 1, bf16><<<g, 256, 0, stream>>>(hA, Wt5, nullptr, dis, hB, N, 512, 1024);
        agg_vec_kernel<512, 1, 1, 0, bf16, bf16><<<cdiv((long long)N * 64, T), T, 0, stream>>>(
            hB, offsets, csr_src, dis, bf_[5], hA, N);
    }

    // L6: MFMA (rowscale) -> hB (g-form); agg_vec (+b6,relu) -> hA
    {
        dim3 g(256 / 128, cdiv(N, 128));
        gemm_mfma_kernel<0, 0, 1, bf16><<<g, 256, 0, stream>>>(hA, Wt6, nullptr, dis, hB, N, 256, 512);
        agg_vec_kernel<256, 1, 1, 0, bf16, bf16><<<cdiv((long long)N * 32, T), T, 0, stream>>>(
            hB, offsets, csr_src, dis, bf_[6], hA, N);
    }

    // L7: naive gemm bf16->f32 -> fB; legacy scalar agg (+b7, no relu) -> fA
    {
        gemm_naive_kernel<bf16, float><<<cdiv((long long)N * 2, T), T, 0, stream>>>(
            hA, Wf[7], nullptr, fB, N, 2, 256, 0, 0);
        agg_kernel<float, float><<<cdiv((long long)N * 2, T), T, 0, stream>>>(
            fB, offsets, csr_src, dis, bf_[7], fA, N, 2, 1, 0);
    }

    out_kernel<<<cdiv((long long)N * 2, T), T, 0, stream>>>(fA, d_out, N * 2, flag);
}